// Round 1
// baseline (155.834 us; speedup 1.0000x reference)
//
#include <hip/hip_runtime.h>
#include <math.h>

// DETR-style loss with per-batch Hungarian matching.
// B=256 batches, S=64 slots, stroke dim 10, target dim 11 (last = validity).
//
// Strategy: one block of 64 threads (one wave) per batch. Jonker-Volgenant
// (e-maxx variant, identical to the numpy reference) run on the TRANSPOSED
// cost matrix (rows = valid gts (n=ng), cols = preds (m=64)) -- which is
// exactly the path the reference takes whenever ng < 64 (always, in practice).
// Cost built in fp32 with numpy's pairwise-tree order, matching in fp64 so
// every branch decision is bit-identical to the numpy reference.

#define SS 64

__global__ __launch_bounds__(64) void detr_match_loss_kernel(
    const float* __restrict__ pred_strokes,   // [B,64,10]
    const float* __restrict__ pred_validity,  // [B,64,1]
    const float* __restrict__ targets,        // [B,64,11]
    double* __restrict__ loss_ws)             // [B] per-batch loss
{
    const int b = blockIdx.x;
    const int t = threadIdx.x;   // 0..63; owns cost column t+1 (pred t)
    const float* ps = pred_strokes  + (size_t)b * SS * 10;
    const float* pv = pred_validity + (size_t)b * SS;
    const float* tg = targets      + (size_t)b * SS * 11;

    __shared__ double C[SS * SS];                    // [ng][64] cost, fp64
    __shared__ double u[SS + 1], v[SS + 1], minv[SS + 1];
    __shared__ int p[SS + 1], way[SS + 1], used[SS + 1];
    __shared__ int vidx[SS];                         // compacted valid gt idx
    __shared__ int col4row[SS];                      // gt-row -> pred col
    __shared__ int sh_ng;

    // --- compact valid targets (serial; 64 iters, trivial) ---
    if (t == 0) {
        int ng = 0;
        for (int s = 0; s < SS; ++s)
            if (tg[s * 11 + 10] > 0.5f) vidx[ng++] = s;
        sh_ng = ng;
    }
    __syncthreads();
    const int ng = sh_ng;

    // --- BCE term: thread t handles slot t ---
    double bterm;
    {
        float pvv = pv[t];
        float gv  = tg[t * 11 + 10];
        float lp  = fmaxf(logf(pvv), -100.0f);
        float l1p = fmaxf(logf(1.0f - pvv), -100.0f);
        bterm = -((double)gv * (double)lp + (double)(1.0f - gv) * (double)l1p);
    }

    double csum = 0.0, wsum = 0.0;

    if (ng > 0) {
        // --- cost matrix: C[i][t] = cost(gt row i, pred t), fp32 -> fp64 ---
        const float* pp = ps + t * 10;
        float p0 = pp[0], p1 = pp[1], p2 = pp[2], p3 = pp[3], p4 = pp[4];
        float p5 = pp[5], p6 = pp[6], p7 = pp[7], p8 = pp[8], p9 = pp[9];
        for (int i = 0; i < ng; ++i) {
            const float* gt = tg + vidx[i] * 11;
            float d0 = fabsf(p0 - gt[0]);
            float d1 = fabsf(p1 - gt[1]);
            float d2 = fabsf(p2 - gt[2]);
            float d3 = fabsf(p3 - gt[3]);
            float d4 = fabsf(p4 - gt[4]);
            float d5 = fabsf(p5 - gt[5]);
            float d6 = fabsf(p6 - gt[6]);
            float d7 = fabsf(p7 - gt[7]);
            float d8 = fabsf(p8 - gt[8]);
            float d9 = fabsf(p9 - gt[9]);
            // numpy pairwise-tree order for 8 elements
            float cs = ((d0 + d1) + (d2 + d3)) + ((d4 + d5) + (d6 + d7));
            float wd = d8 + d9;
            float c;
            {
#pragma clang fp contract(off)
                c = 5.0f * cs + wd;   // no fma: match numpy mul-then-add
            }
            C[i * SS + t] = (double)c;
        }
        // --- init potentials ---
        u[t] = 0.0; v[t] = 0.0; p[t] = 0;
        if (t == 0) { u[SS] = 0.0; v[SS] = 0.0; p[SS] = 0; }
        __syncthreads();

        // --- JV rows ---
        for (int i = 1; i <= ng; ++i) {
            minv[t + 1] = (double)INFINITY;
            used[t + 1] = 0;
            way[t + 1]  = 0;
            if (t == 0) p[0] = i;
            __syncthreads();

            int j0 = 0;
            for (;;) {
                if (j0 == t + 1) used[t + 1] = 1;   // own-column mark
                const int i0 = p[j0];               // p stable inside loop
                const bool un = (used[t + 1] == 0);
                double mv = (double)INFINITY;
                if (un) {
                    double cur = (C[(i0 - 1) * SS + t] - u[i0]) - v[t + 1];
                    if (cur < minv[t + 1]) { minv[t + 1] = cur; way[t + 1] = j0; }
                    mv = minv[t + 1];
                }
                // argmin over unused columns; ties -> smallest index (numpy)
                double bv = mv; int bj = t + 1;
                for (int off = 1; off < 64; off <<= 1) {
                    double ov = __shfl_xor(bv, off, 64);
                    int    oj = __shfl_xor(bj, off, 64);
                    if (ov < bv || (ov == bv && oj < bj)) { bv = ov; bj = oj; }
                }
                const double delta = bv;
                const int    j1    = bj;
                // updates (all distinct LDS addresses across lanes)
                if (un) {
                    minv[t + 1] -= delta;
                } else {
                    u[p[t + 1]] += delta;
                    v[t + 1]    -= delta;
                }
                if (t == 0) { u[p[0]] += delta; v[0] -= delta; } // virtual col 0
                j0 = j1;
                if (p[j1] == 0) break;     // uniform break
                __syncthreads();           // update -> next-iter reads of u
            }
            __syncthreads();               // way[] writes -> augment reads
            if (t == 0) {
                int jj = j0;
                while (jj) { const int jn = way[jj]; p[jj] = p[jn]; jj = jn; }
            }
            __syncthreads();
        }

        // --- extract assignment: p[j]=row (1-based) matched to column j ---
        {
            const int r = p[t + 1];
            if (r > 0) col4row[r - 1] = t;
        }
        __syncthreads();

        // --- matched L1 sums: thread t handles gt-row t (t < ng) ---
        if (t < ng) {
            const float* gt = tg + vidx[t] * 11;
            const float* mp = ps + col4row[t] * 10;
#pragma unroll
            for (int k = 0; k < 8; ++k) csum += (double)fabsf(mp[k] - gt[k]);
            wsum = (double)fabsf(mp[8] - gt[8]) + (double)fabsf(mp[9] - gt[9]);
        }
    }

    // --- wave reductions (sum) ---
    double s0 = csum, s1 = wsum, s2 = bterm;
    for (int off = 1; off < 64; off <<= 1) {
        s0 += __shfl_xor(s0, off, 64);
        s1 += __shfl_xor(s1, off, 64);
        s2 += __shfl_xor(s2, off, 64);
    }
    if (t == 0) {
        const double bce = s2 / 64.0;
        const double loss = (ng > 0)
            ? 5.0 * (s0 / ((double)ng * 8.0)) + (s1 / ((double)ng * 2.0)) + bce
            : bce;
        loss_ws[b] = loss;
    }
}

__global__ __launch_bounds__(256) void detr_reduce_kernel(
    const double* __restrict__ ws, float* __restrict__ out, int B)
{
    const int t = threadIdx.x;
    double x = 0.0;
    for (int idx = t; idx < B; idx += 256) x += ws[idx];
    for (int off = 1; off < 64; off <<= 1) x += __shfl_xor(x, off, 64);
    __shared__ double part[4];
    if ((t & 63) == 0) part[t >> 6] = x;
    __syncthreads();
    if (t == 0) {
        double s = part[0] + part[1] + part[2] + part[3];
        out[0] = (float)(s / (double)B);
    }
}

extern "C" void kernel_launch(void* const* d_in, const int* in_sizes, int n_in,
                              void* d_out, int out_size, void* d_ws, size_t ws_size,
                              hipStream_t stream) {
    const float* ps = (const float*)d_in[0];
    const float* pv = (const float*)d_in[1];
    const float* tg = (const float*)d_in[2];
    float* out = (float*)d_out;
    double* ws = (double*)d_ws;
    const int B = in_sizes[0] / (SS * 10);

    detr_match_loss_kernel<<<B, SS, 0, stream>>>(ps, pv, tg, ws);
    detr_reduce_kernel<<<1, 256, 0, stream>>>(ws, out, B);
}

// Round 2
// 100.145 us; speedup vs baseline: 1.5561x; 1.5561x over previous
//
#include <hip/hip_runtime.h>
#include <math.h>

// DETR loss with per-batch Hungarian (Jonker-Volgenant, e-maxx variant,
// bit-exact vs the numpy reference on the transposed cost matrix).
//
// One block = one wave (64 lanes) per batch. Lane t owns cost column t+1
// (pred t). All per-column state (v, minv, way, used, p) lives in REGISTERS;
// cross-lane access uses readlane/ballot/shfl (wave-uniform indices). Only
// the cost matrix (fp32), the row potentials u (fp64, exact accumulation),
// and two small index arrays live in LDS. No __syncthreads anywhere:
// single-wave lockstep + in-order per-wave LDS processing; asm fences with
// memory clobber pin the (cold-path) orderings.

#define SS 64
#define LDS_FENCE() asm volatile("s_waitcnt lgkmcnt(0)" ::: "memory")

__device__ __forceinline__ int rlane_i(int x, int lane) {
    return __builtin_amdgcn_readlane(x, lane);
}

__global__ __launch_bounds__(64) void detr_match_loss_kernel(
    const float* __restrict__ pred_strokes,   // [B,64,10]
    const float* __restrict__ pred_validity,  // [B,64,1]
    const float* __restrict__ targets,        // [B,64,11]
    double* __restrict__ loss_ws)             // [B]
{
    const int b = blockIdx.x;
    const int t = threadIdx.x;   // lane; owns column j = t+1
    const float* ps = pred_strokes  + (size_t)b * SS * 10;
    const float* pv = pred_validity + (size_t)b * SS;
    const float* tg = targets      + (size_t)b * SS * 11;

    __shared__ float  Cs[SS * SS];     // cost (fp32 exact), [row][64]
    __shared__ float  tgs[SS * 11];    // staged targets
    __shared__ double u_lds[SS + 1];   // row potentials (exact fp64 accum)
    __shared__ int    vidx[SS];        // compacted valid gt indices
    __shared__ int    col4row[SS];     // gt-row -> pred col

    // --- stage targets (coalesced) ---
#pragma unroll
    for (int k = 0; k < 11; ++k) tgs[k * SS + t] = tg[k * SS + t];
    LDS_FENCE();

    // --- valid compaction via ballot/rank ---
    const float gv    = tgs[t * 11 + 10];
    const bool  valid = gv > 0.5f;
    const unsigned long long vmask = __ballot(valid);
    const int ng = __popcll(vmask);
    if (valid) {
        const int rank = __popcll(vmask & ((1ull << t) - 1ull));
        vidx[rank] = t;
    }
    LDS_FENCE();

    // --- BCE term (slot t) ---
    double bterm;
    {
        const float pvv = pv[t];
        const float lp  = fmaxf(logf(pvv), -100.0f);
        const float l1p = fmaxf(logf(1.0f - pvv), -100.0f);
        bterm = -((double)gv * (double)lp + (double)(1.0f - gv) * (double)l1p);
    }

    double csum = 0.0, wsum = 0.0;

    if (ng > 0) {
        // --- cost matrix: Cs[i][t] = cost(gt row i, pred t), fp32 ---
        float pr[10];
#pragma unroll
        for (int k = 0; k < 10; ++k) pr[k] = ps[t * 10 + k];

        for (int i = 0; i < ng; ++i) {
            const float* g = &tgs[vidx[i] * 11];   // broadcast LDS reads
            float d[10];
#pragma unroll
            for (int k = 0; k < 10; ++k) d[k] = fabsf(pr[k] - g[k]);
            const float cs = ((d[0] + d[1]) + (d[2] + d[3]))
                           + ((d[4] + d[5]) + (d[6] + d[7]));   // numpy tree
            const float wd = d[8] + d[9];
            float c;
            {
#pragma clang fp contract(off)
                c = 5.0f * cs + wd;                // mul-then-add, no fma
            }
            Cs[i * SS + t] = c;
        }
        LDS_FENCE();

        // --- JV matcher; per-lane register state for column t+1 ---
        double v_j = 0.0;   // v[t+1]
        int    p_j = 0;     // p[t+1] (matched row, 0 = none)

        for (int i = 1; i <= ng; ++i) {
            double minv_j = __builtin_inf();
            int    way_j  = 0;
            bool   used_j = false;
            double usum   = 0.0;          // u[i] running sum (exact order)
            double u0     = 0.0;          // u[i0] for current j0
            int    j0     = 0;
            float  Cval   = Cs[(i - 1) * SS + t];  // C[i0-1][t]

            for (;;) {
                if (t + 1 == j0) used_j = true;
                const double cur = ((double)Cval - u0) - v_j;
                if (!used_j && cur < minv_j) { minv_j = cur; way_j = j0; }

                // min over unused columns, then first-index via ballot
                const double mvl = used_j ? __builtin_inf() : minv_j;
                double m = mvl;
#pragma unroll
                for (int off = 1; off < 64; off <<= 1)
                    m = fmin(m, __shfl_xor(m, off, 64));
                const unsigned long long bal = __ballot(mvl == m);
                const int j1 = __builtin_amdgcn_readfirstlane(
                                   __ffsll((unsigned long long)bal)); // col = lane+1
                const int i1 = rlane_i(p_j, j1 - 1);                  // p[j1]

                // prefetch next iteration's u[i1], C[i1-1][t] BEFORE the
                // delta updates (row i1 is not in this iteration's update
                // set: j1 was unused) -- hides LDS latency.
                double u_next = 0.0; float C_next = 0.0f;
                if (i1 != 0) {
                    u_next = u_lds[i1];
                    C_next = Cs[(i1 - 1) * SS + t];
                }

                // updates (reference applies them even on the final iter)
                usum += m;                       // u[i] += delta (col 0 used)
                if (used_j) {
                    v_j -= m;
                    u_lds[p_j] += m;             // distinct rows: no collision
                } else {
                    minv_j -= m;
                }

                j0 = j1;
                if (i1 == 0) break;              // reached unmatched column
                u0 = u_next; Cval = C_next;
            }

            // --- augment along way[] (readlane pointer chase, short) ---
            int jj = j0;
            while (jj != 0) {
                const int jp   = rlane_i(way_j, jj - 1);
                const int pnew = (jp == 0) ? i : rlane_i(p_j, jp - 1);
                if (t == jj - 1) p_j = pnew;
                jj = jp;
            }
            if (t == 0) u_lds[i] = usum;         // commit u[i] for later phases
            LDS_FENCE();
        }

        // --- extract assignment ---
        if (p_j > 0) col4row[p_j - 1] = t;
        LDS_FENCE();

        // --- matched L1 sums: thread t handles gt-row t (t < ng) ---
        if (t < ng) {
            const float* g  = &tgs[vidx[t] * 11];
            const float* mp = ps + col4row[t] * 10;
#pragma unroll
            for (int k = 0; k < 8; ++k) csum += (double)fabsf(mp[k] - g[k]);
            wsum = (double)fabsf(mp[8] - g[8]) + (double)fabsf(mp[9] - g[9]);
        }
    }

    // --- wave reductions (identical to round-1 epilogue) ---
    double s0 = csum, s1 = wsum, s2 = bterm;
#pragma unroll
    for (int off = 1; off < 64; off <<= 1) {
        s0 += __shfl_xor(s0, off, 64);
        s1 += __shfl_xor(s1, off, 64);
        s2 += __shfl_xor(s2, off, 64);
    }
    if (t == 0) {
        const double bce = s2 / 64.0;
        const double loss = (ng > 0)
            ? 5.0 * (s0 / ((double)ng * 8.0)) + (s1 / ((double)ng * 2.0)) + bce
            : bce;
        loss_ws[b] = loss;
    }
}

__global__ __launch_bounds__(256) void detr_reduce_kernel(
    const double* __restrict__ ws, float* __restrict__ out, int B)
{
    const int t = threadIdx.x;
    double x = 0.0;
    for (int idx = t; idx < B; idx += 256) x += ws[idx];
    for (int off = 1; off < 64; off <<= 1) x += __shfl_xor(x, off, 64);
    __shared__ double part[4];
    if ((t & 63) == 0) part[t >> 6] = x;
    __syncthreads();
    if (t == 0) {
        double s = part[0] + part[1] + part[2] + part[3];
        out[0] = (float)(s / (double)B);
    }
}

extern "C" void kernel_launch(void* const* d_in, const int* in_sizes, int n_in,
                              void* d_out, int out_size, void* d_ws, size_t ws_size,
                              hipStream_t stream) {
    const float* ps = (const float*)d_in[0];
    const float* pv = (const float*)d_in[1];
    const float* tg = (const float*)d_in[2];
    float* out = (float*)d_out;
    double* ws = (double*)d_ws;
    const int B = in_sizes[0] / (SS * 10);

    detr_match_loss_kernel<<<B, SS, 0, stream>>>(ps, pv, tg, ws);
    detr_reduce_kernel<<<1, 256, 0, stream>>>(ws, out, B);
}

// Round 3
// 89.621 us; speedup vs baseline: 1.7388x; 1.1174x over previous
//
#include <hip/hip_runtime.h>
#include <math.h>

// DETR loss with per-batch Hungarian (Jonker-Volgenant, e-maxx variant,
// bit-exact vs the numpy reference on the transposed cost matrix).
//
// One block = one wave (64 lanes) per batch. Lane t owns cost column t+1
// (pred t). Per-column state (v, minv, way, used, p) in registers; the
// wave-wide min of minv uses a DPP chain on the VALU pipe (row_shr 1/2/4/8,
// row_bcast15, row_bcast31 -> lane 63), NOT __shfl (ds_bpermute, LDS pipe,
// ~40cy/op) -- this is the inner loop's critical path. Argmin tie-breaking
// (numpy: first index attaining the min) via v_cmp_eq_f64 + ballot + ffs.
// u (row potentials) stays in LDS with the reference's exact accumulation
// order; single-wave in-order LDS pipe means no syncthreads/waitcnt needed
// between dependent ds ops.

#define SS 64
#define LDS_FENCE() asm volatile("s_waitcnt lgkmcnt(0)" ::: "memory")

__device__ __forceinline__ int rlane_i(int x, int lane) {
    return __builtin_amdgcn_readlane(x, lane);
}

// DPP-shifted copy of x; lanes with no source get +inf (min identity).
template<int CTRL>
__device__ __forceinline__ double dpp_shift_inf(double x) {
    const int lo = __builtin_amdgcn_update_dpp(
        0x00000000, __double2loint(x), CTRL, 0xF, 0xF, false);
    const int hi = __builtin_amdgcn_update_dpp(
        0x7FF00000, __double2hiint(x), CTRL, 0xF, 0xF, false);
    return __hiloint2double(hi, lo);
}

// After this, lane 63 holds min over all 64 lanes (other lanes partial).
__device__ __forceinline__ double wave_min_f64_to63(double x) {
    x = fmin(x, dpp_shift_inf<0x111>(x));  // row_shr:1
    x = fmin(x, dpp_shift_inf<0x112>(x));  // row_shr:2
    x = fmin(x, dpp_shift_inf<0x114>(x));  // row_shr:4
    x = fmin(x, dpp_shift_inf<0x118>(x));  // row_shr:8
    x = fmin(x, dpp_shift_inf<0x142>(x));  // row_bcast15
    x = fmin(x, dpp_shift_inf<0x143>(x));  // row_bcast31
    return x;
}

__global__ __launch_bounds__(64) void detr_match_loss_kernel(
    const float* __restrict__ pred_strokes,   // [B,64,10]
    const float* __restrict__ pred_validity,  // [B,64,1]
    const float* __restrict__ targets,        // [B,64,11]
    double* __restrict__ loss_ws)             // [B]
{
    const int b = blockIdx.x;
    const int t = threadIdx.x;   // lane; owns column j = t+1
    const float* ps = pred_strokes  + (size_t)b * SS * 10;
    const float* pv = pred_validity + (size_t)b * SS;
    const float* tg = targets      + (size_t)b * SS * 11;

    __shared__ float  Cs[SS * SS];     // cost (fp32 exact), [row][64]
    __shared__ float  tgs[SS * 11];    // staged targets
    __shared__ double u_lds[SS + 1];   // row potentials (exact fp64 accum)
    __shared__ int    vidx[SS];        // compacted valid gt indices
    __shared__ int    col4row[SS];     // gt-row -> pred col

    // --- stage targets (coalesced) ---
#pragma unroll
    for (int k = 0; k < 11; ++k) tgs[k * SS + t] = tg[k * SS + t];
    LDS_FENCE();

    // --- valid compaction via ballot/rank ---
    const float gv    = tgs[t * 11 + 10];
    const bool  valid = gv > 0.5f;
    const unsigned long long vmask = __ballot(valid);
    const int ng = __popcll(vmask);
    if (valid) {
        const int rank = __popcll(vmask & ((1ull << t) - 1ull));
        vidx[rank] = t;
    }
    LDS_FENCE();

    // --- BCE term (slot t) ---
    double bterm;
    {
        const float pvv = pv[t];
        const float lp  = fmaxf(logf(pvv), -100.0f);
        const float l1p = fmaxf(logf(1.0f - pvv), -100.0f);
        bterm = -((double)gv * (double)lp + (double)(1.0f - gv) * (double)l1p);
    }

    double csum = 0.0, wsum = 0.0;

    if (ng > 0) {
        // --- cost matrix: Cs[i][t] = cost(gt row i, pred t), fp32 ---
        float pr[10];
#pragma unroll
        for (int k = 0; k < 10; ++k) pr[k] = ps[t * 10 + k];

        for (int i = 0; i < ng; ++i) {
            const float* g = &tgs[vidx[i] * 11];   // broadcast LDS reads
            float d[10];
#pragma unroll
            for (int k = 0; k < 10; ++k) d[k] = fabsf(pr[k] - g[k]);
            const float cs = ((d[0] + d[1]) + (d[2] + d[3]))
                           + ((d[4] + d[5]) + (d[6] + d[7]));   // numpy tree
            const float wd = d[8] + d[9];
            float c;
            {
#pragma clang fp contract(off)
                c = 5.0f * cs + wd;                // mul-then-add, no fma
            }
            Cs[i * SS + t] = c;
        }
        // no fence: each lane only ever reads its own column of Cs.

        // --- JV matcher; per-lane register state for column t+1 ---
        double v_j = 0.0;   // v[t+1]
        int    p_j = 0;     // p[t+1] (matched row, 0 = none)
        float  Chead = Cs[0 * SS + t];             // row 1 entry, prefetched

        for (int i = 1; i <= ng; ++i) {
            double minv_j = __builtin_inf();
            int    way_j  = 0;
            bool   used_j = false;
            double usum   = 0.0;          // u[i] running sum (exact order)
            double u0     = 0.0;          // u[i0] for current j0
            int    j0     = 0;
            float  Cval   = Chead;        // C[i0-1][t]

            for (;;) {
                if (t + 1 == j0) used_j = true;
                const double cur = ((double)Cval - u0) - v_j;
                if (!used_j && cur < minv_j) { minv_j = cur; way_j = j0; }

                // wave min on VALU pipe (DPP), then first-index via ballot
                const double mvl = used_j ? __builtin_inf() : minv_j;
                const double mr  = wave_min_f64_to63(mvl);
                const double delta = __hiloint2double(
                    rlane_i(__double2hiint(mr), 63),
                    rlane_i(__double2loint(mr), 63));
                const unsigned long long bal = __ballot(mvl == delta);
                const int j1 = __ffsll(bal);                 // col = lane+1
                const int i1 = rlane_i(p_j, j1 - 1);         // p[j1]

                // prefetch next iteration's u[i1], C[i1-1][t] BEFORE the
                // delta updates (row i1 is not in this iteration's update
                // set: j1 was unused) -- hides LDS latency.
                double u_next = 0.0; float C_next = 0.0f;
                if (i1 != 0) {
                    u_next = u_lds[i1];
                    C_next = Cs[(i1 - 1) * SS + t];
                }

                // updates (reference applies them even on the final iter)
                usum += delta;                   // u[i] += delta (col 0 used)
                if (used_j) {
                    v_j -= delta;
                    u_lds[p_j] += delta;         // distinct rows: no collision
                } else {
                    minv_j -= delta;
                }

                j0 = j1;
                if (i1 == 0) break;              // reached unmatched column
                u0 = u_next; Cval = C_next;
            }

            // prefetch next row's C entry; hides under the augment chase
            Chead = (i < ng) ? Cs[i * SS + t] : 0.0f;

            // --- augment along way[] (readlane pointer chase, short) ---
            int jj = j0;
            while (jj != 0) {
                const int jp   = rlane_i(way_j, jj - 1);
                const int pnew = (jp == 0) ? i : rlane_i(p_j, jp - 1);
                if (t == jj - 1) p_j = pnew;
                jj = jp;
            }
            if (t == 0) u_lds[i] = usum;   // commit u[i]; in-order LDS pipe
        }

        // --- extract assignment ---
        if (p_j > 0) col4row[p_j - 1] = t;
        LDS_FENCE();

        // --- matched L1 sums: thread t handles gt-row t (t < ng) ---
        if (t < ng) {
            const float* g  = &tgs[vidx[t] * 11];
            const float* mp = ps + col4row[t] * 10;
#pragma unroll
            for (int k = 0; k < 8; ++k) csum += (double)fabsf(mp[k] - g[k]);
            wsum = (double)fabsf(mp[8] - g[8]) + (double)fabsf(mp[9] - g[9]);
        }
    }

    // --- wave reductions (identical to round-1/2 epilogue; cold path) ---
    double s0 = csum, s1 = wsum, s2 = bterm;
#pragma unroll
    for (int off = 1; off < 64; off <<= 1) {
        s0 += __shfl_xor(s0, off, 64);
        s1 += __shfl_xor(s1, off, 64);
        s2 += __shfl_xor(s2, off, 64);
    }
    if (t == 0) {
        const double bce = s2 / 64.0;
        const double loss = (ng > 0)
            ? 5.0 * (s0 / ((double)ng * 8.0)) + (s1 / ((double)ng * 2.0)) + bce
            : bce;
        loss_ws[b] = loss;
    }
}

__global__ __launch_bounds__(256) void detr_reduce_kernel(
    const double* __restrict__ ws, float* __restrict__ out, int B)
{
    const int t = threadIdx.x;
    double x = 0.0;
    for (int idx = t; idx < B; idx += 256) x += ws[idx];
    for (int off = 1; off < 64; off <<= 1) x += __shfl_xor(x, off, 64);
    __shared__ double part[4];
    if ((t & 63) == 0) part[t >> 6] = x;
    __syncthreads();
    if (t == 0) {
        double s = part[0] + part[1] + part[2] + part[3];
        out[0] = (float)(s / (double)B);
    }
}

extern "C" void kernel_launch(void* const* d_in, const int* in_sizes, int n_in,
                              void* d_out, int out_size, void* d_ws, size_t ws_size,
                              hipStream_t stream) {
    const float* ps = (const float*)d_in[0];
    const float* pv = (const float*)d_in[1];
    const float* tg = (const float*)d_in[2];
    float* out = (float*)d_out;
    double* ws = (double*)d_ws;
    const int B = in_sizes[0] / (SS * 10);

    detr_match_loss_kernel<<<B, SS, 0, stream>>>(ps, pv, tg, ws);
    detr_reduce_kernel<<<1, 256, 0, stream>>>(ws, out, B);
}

// Round 4
// 86.140 us; speedup vs baseline: 1.8091x; 1.0404x over previous
//
#include <hip/hip_runtime.h>
#include <math.h>

// DETR loss with per-batch Hungarian (Jonker-Volgenant, e-maxx variant,
// bit-exact vs the numpy reference on the transposed cost matrix).
//
// One block = one wave (64 lanes) per batch; lane t owns cost column t+1
// (pred t). ALL matcher state is in registers:
//   - per-column: v_j, minv_j, way_j, used_j, p_j   (lane t = column t+1)
//   - per-row:    u_reg (lane r = row r+1), row_used flag
// u[p[used]] += delta becomes a predicated VALU add (row_used lanes); the
// u[i0] broadcast is v_readlane x2 (~8cy) instead of a ~120cy ds_read.
// Wave argmin runs a 6-step DPP v_min_u32 chain on the hi32 of minv
// (nonneg f64: value order == (hi,lo) unsigned lex order), with a rare
// wave-uniform lo32 fallback on exact hi ties; delta is the selected
// lane's full f64 minv (bit-exact), ffs-on-ballot = numpy first-index
// tie-break. Only remaining LDS in the hot loop: one prefetched fp32
// cost read (own column -> bank-conflict-free, issued speculatively
// right after the hi-ballot).

#define SS 64
#define LDS_FENCE() asm volatile("s_waitcnt lgkmcnt(0)" ::: "memory")

__device__ __forceinline__ int rlane_i(int x, int lane) {
    return __builtin_amdgcn_readlane(x, lane);
}
__device__ __forceinline__ double rlane_d(double x, int lane) {
    return __hiloint2double(rlane_i(__double2hiint(x), lane),
                            rlane_i(__double2loint(x), lane));
}

// DPP-shifted copy of x; lanes with no source get 0xFFFFFFFF (u32-min id).
template<int CTRL>
__device__ __forceinline__ unsigned dpp_shift_ff(unsigned x) {
    return (unsigned)__builtin_amdgcn_update_dpp(
        (int)0xFFFFFFFFu, (int)x, CTRL, 0xF, 0xF, false);
}
// After this, lane 63 holds the u32 min over all 64 lanes.
__device__ __forceinline__ unsigned wave_min_u32_to63(unsigned x) {
    unsigned y;
    y = dpp_shift_ff<0x111>(x); x = x < y ? x : y;  // row_shr:1
    y = dpp_shift_ff<0x112>(x); x = x < y ? x : y;  // row_shr:2
    y = dpp_shift_ff<0x114>(x); x = x < y ? x : y;  // row_shr:4
    y = dpp_shift_ff<0x118>(x); x = x < y ? x : y;  // row_shr:8
    y = dpp_shift_ff<0x142>(x); x = x < y ? x : y;  // row_bcast15
    y = dpp_shift_ff<0x143>(x); x = x < y ? x : y;  // row_bcast31
    return x;
}

__global__ __launch_bounds__(64) void detr_match_loss_kernel(
    const float* __restrict__ pred_strokes,   // [B,64,10]
    const float* __restrict__ pred_validity,  // [B,64,1]
    const float* __restrict__ targets,        // [B,64,11]
    double* __restrict__ loss_ws)             // [B]
{
    const int b = blockIdx.x;
    const int t = threadIdx.x;   // lane; owns column j = t+1, row t+1
    const float* ps = pred_strokes  + (size_t)b * SS * 10;
    const float* pv = pred_validity + (size_t)b * SS;
    const float* tg = targets      + (size_t)b * SS * 11;

    __shared__ float  Cs[SS * SS];     // cost (fp32 exact), [row][64]
    __shared__ float  tgs[SS * 11];    // staged targets
    __shared__ int    vidx[SS];        // compacted valid gt indices
    __shared__ int    col4row[SS];     // gt-row -> pred col

    // --- stage targets (coalesced) ---
#pragma unroll
    for (int k = 0; k < 11; ++k) tgs[k * SS + t] = tg[k * SS + t];
    LDS_FENCE();

    // --- valid compaction via ballot/rank ---
    const float gv    = tgs[t * 11 + 10];
    const bool  valid = gv > 0.5f;
    const unsigned long long vmask = __ballot(valid);
    const int ng = __popcll(vmask);
    if (valid) {
        const int rank = __popcll(vmask & ((1ull << t) - 1ull));
        vidx[rank] = t;
    }
    LDS_FENCE();

    // --- BCE term (slot t) ---
    double bterm;
    {
        const float pvv = pv[t];
        const float lp  = fmaxf(logf(pvv), -100.0f);
        const float l1p = fmaxf(logf(1.0f - pvv), -100.0f);
        bterm = -((double)gv * (double)lp + (double)(1.0f - gv) * (double)l1p);
    }

    double csum = 0.0, wsum = 0.0;

    if (ng > 0) {
        // --- cost matrix: Cs[i][t] = cost(gt row i, pred t), fp32 ---
        float pr[10];
#pragma unroll
        for (int k = 0; k < 10; ++k) pr[k] = ps[t * 10 + k];

        for (int i = 0; i < ng; ++i) {
            const float* g = &tgs[vidx[i] * 11];   // broadcast LDS reads
            float d[10];
#pragma unroll
            for (int k = 0; k < 10; ++k) d[k] = fabsf(pr[k] - g[k]);
            const float cs = ((d[0] + d[1]) + (d[2] + d[3]))
                           + ((d[4] + d[5]) + (d[6] + d[7]));   // numpy tree
            const float wd = d[8] + d[9];
            float c;
            {
#pragma clang fp contract(off)
                c = 5.0f * cs + wd;                // mul-then-add, no fma
            }
            Cs[i * SS + t] = c;
        }
        // no fence: each lane only ever reads its own column of Cs.

        // --- JV matcher; all state in registers ---
        double v_j   = 0.0;   // v[t+1]
        double u_reg = 0.0;   // u[t+1] (lane t = row t+1)
        int    p_j   = 0;     // p[t+1] (matched row, 0 = none)
        float  Chead = Cs[t]; // row 1 entry, prefetched

        for (int i = 1; i <= ng; ++i) {
            double minv_j   = __builtin_inf();
            int    way_j    = 0;
            bool   used_j   = false;
            bool   row_used = (t == i - 1);   // p[0] = i
            double u0       = 0.0;            // u[i] == 0 at phase start
            int    j0       = 0;
            float  Cval     = Chead;          // C[i0-1][t]

            for (;;) {
                used_j = used_j || (t + 1 == j0);
                const double cur = ((double)Cval - u0) - v_j;
                if (!used_j && cur < minv_j) { minv_j = cur; way_j = j0; }

                // wave argmin via u32 DPP chain on hi32 (nonneg doubles)
                const unsigned key = used_j ? 0x7FF00000u
                                            : (unsigned)__double2hiint(minv_j);
                const unsigned kr    = wave_min_u32_to63(key);
                const unsigned hstar = (unsigned)rlane_i((int)kr, 63);
                unsigned long long bal = __ballot(key == hstar);
                int j1 = __ffsll(bal);                       // col = lane+1
                int i1 = rlane_i(p_j, j1 - 1);               // p[j1]

                // speculative prefetch of next C entry (correct unless the
                // rare exact-hi32 tie below revises j1)
                float C_next = 0.0f;
                if (i1 != 0) C_next = Cs[(i1 - 1) * SS + t];

                if (__popcll(bal) > 1) {      // rare: resolve lo32 among ties
                    const unsigned lo = (key == hstar)
                        ? (unsigned)__double2loint(minv_j) : 0xFFFFFFFFu;
                    const unsigned lr    = wave_min_u32_to63(lo);
                    const unsigned lstar = (unsigned)rlane_i((int)lr, 63);
                    bal = __ballot(key == hstar && lo == lstar);
                    j1  = __ffsll(bal);
                    i1  = rlane_i(p_j, j1 - 1);
                    if (i1 != 0) C_next = Cs[(i1 - 1) * SS + t];
                }

                const double delta  = rlane_d(minv_j, j1 - 1);
                const double u_next = (i1 != 0) ? rlane_d(u_reg, i1 - 1) : 0.0;
                // (row i1 is not row_used this iteration, so u_next is
                //  unaffected by the predicated add below -- matches the
                //  reference, where u[i1] gets deltas only once j1 is used.)

                // updates (reference applies them even on the final iter)
                if (row_used) u_reg += delta;     // u[p[used]] += delta
                if (used_j)   v_j   -= delta;     // v[used]    -= delta
                else          minv_j -= delta;    // minv[unused] -= delta
                row_used = row_used || (t == i1 - 1);  // row i1 used from next iter

                j0 = j1;
                if (i1 == 0) break;               // reached unmatched column
                u0 = u_next; Cval = C_next;
            }

            // prefetch next row's C entry; hides under the augment chase
            Chead = (i < ng) ? Cs[i * SS + t] : 0.0f;

            // --- augment along way[] (readlane pointer chase, short) ---
            int jj = j0;
            while (jj != 0) {
                const int jp   = rlane_i(way_j, jj - 1);
                const int pnew = (jp == 0) ? i : rlane_i(p_j, jp - 1);
                if (t == jj - 1) p_j = pnew;
                jj = jp;
            }
        }

        // --- extract assignment ---
        if (p_j > 0) col4row[p_j - 1] = t;
        LDS_FENCE();

        // --- matched L1 sums: thread t handles gt-row t (t < ng) ---
        if (t < ng) {
            const float* g  = &tgs[vidx[t] * 11];
            const float* mp = ps + col4row[t] * 10;
#pragma unroll
            for (int k = 0; k < 8; ++k) csum += (double)fabsf(mp[k] - g[k]);
            wsum = (double)fabsf(mp[8] - g[8]) + (double)fabsf(mp[9] - g[9]);
        }
    }

    // --- wave reductions (identical epilogue to rounds 1-3; cold path) ---
    double s0 = csum, s1 = wsum, s2 = bterm;
#pragma unroll
    for (int off = 1; off < 64; off <<= 1) {
        s0 += __shfl_xor(s0, off, 64);
        s1 += __shfl_xor(s1, off, 64);
        s2 += __shfl_xor(s2, off, 64);
    }
    if (t == 0) {
        const double bce = s2 / 64.0;
        const double loss = (ng > 0)
            ? 5.0 * (s0 / ((double)ng * 8.0)) + (s1 / ((double)ng * 2.0)) + bce
            : bce;
        loss_ws[b] = loss;
    }
}

__global__ __launch_bounds__(256) void detr_reduce_kernel(
    const double* __restrict__ ws, float* __restrict__ out, int B)
{
    const int t = threadIdx.x;
    double x = 0.0;
    for (int idx = t; idx < B; idx += 256) x += ws[idx];
    for (int off = 1; off < 64; off <<= 1) x += __shfl_xor(x, off, 64);
    __shared__ double part[4];
    if ((t & 63) == 0) part[t >> 6] = x;
    __syncthreads();
    if (t == 0) {
        double s = part[0] + part[1] + part[2] + part[3];
        out[0] = (float)(s / (double)B);
    }
}

extern "C" void kernel_launch(void* const* d_in, const int* in_sizes, int n_in,
                              void* d_out, int out_size, void* d_ws, size_t ws_size,
                              hipStream_t stream) {
    const float* ps = (const float*)d_in[0];
    const float* pv = (const float*)d_in[1];
    const float* tg = (const float*)d_in[2];
    float* out = (float*)d_out;
    double* ws = (double*)d_ws;
    const int B = in_sizes[0] / (SS * 10);

    detr_match_loss_kernel<<<B, SS, 0, stream>>>(ps, pv, tg, ws);
    detr_reduce_kernel<<<1, 256, 0, stream>>>(ws, out, B);
}

// Round 7
// 84.553 us; speedup vs baseline: 1.8430x; 1.0188x over previous
//
#include <hip/hip_runtime.h>
#include <math.h>

// DETR loss with per-batch Hungarian matching (Jonker-Volgenant).
//
// One block = one wave (64 lanes) per batch; lane t owns cost column t+1
// (pred t) and row t+1. All matcher state in registers. Wave argmin = 6-step
// DPP v_min_u32 chain (+ rare lo32 fallback on exact primary ties);
// ffs-on-ballot = first-index tie-break.
//
// Round 7: ROW-reduction init (round 5/6's COLUMN reduction is INVALID for
// rectangular problems: the LP dual needs v_j <= 0 with v_j = 0 on unmatched
// columns; colmin init sets v_j > 0 on all columns -> suboptimal matchings,
// counterexample C=[[1,3,5],[2,3,4]]). Row reduction keeps v == 0:
//   u[i] = rowmin_i (exact fp32 bit value -> claimed edges exactly tight),
//   rows greedily claim their global-argmin column (first-come-wins via a
//   wave-uniform claim mask, no atomics); losing rows stay free and run the
//   verified Dijkstra phase (u0 = u[root] = rowmin now, not 0).
// Feasibility C - u - v >= 0 (u = rowmin), tight matched edges, v <= 0
// maintained by phases => exact optimum. Loss depends only on the
// assignment, which is generically unique for continuous random costs.

#define SS 64
#define LDS_FENCE() asm volatile("s_waitcnt lgkmcnt(0)" ::: "memory")

__device__ __forceinline__ int rlane_i(int x, int lane) {
    return __builtin_amdgcn_readlane(x, lane);
}
__device__ __forceinline__ double rlane_d(double x, int lane) {
    return __hiloint2double(rlane_i(__double2hiint(x), lane),
                            rlane_i(__double2loint(x), lane));
}

// DPP-shifted copy of x; lanes with no source get 0xFFFFFFFF (u32-min id).
template<int CTRL>
__device__ __forceinline__ unsigned dpp_shift_ff(unsigned x) {
    return (unsigned)__builtin_amdgcn_update_dpp(
        (int)0xFFFFFFFFu, (int)x, CTRL, 0xF, 0xF, false);
}
// After this, lane 63 holds the u32 min over all 64 lanes.
__device__ __forceinline__ unsigned wave_min_u32_to63(unsigned x) {
    unsigned y;
    y = dpp_shift_ff<0x111>(x); x = x < y ? x : y;  // row_shr:1
    y = dpp_shift_ff<0x112>(x); x = x < y ? x : y;  // row_shr:2
    y = dpp_shift_ff<0x114>(x); x = x < y ? x : y;  // row_shr:4
    y = dpp_shift_ff<0x118>(x); x = x < y ? x : y;  // row_shr:8
    y = dpp_shift_ff<0x142>(x); x = x < y ? x : y;  // row_bcast15
    y = dpp_shift_ff<0x143>(x); x = x < y ? x : y;  // row_bcast31
    return x;
}

__global__ __launch_bounds__(64) void detr_match_loss_kernel(
    const float* __restrict__ pred_strokes,   // [B,64,10]
    const float* __restrict__ pred_validity,  // [B,64,1]
    const float* __restrict__ targets,        // [B,64,11]
    double* __restrict__ loss_ws)             // [B]
{
    const int b = blockIdx.x;
    const int t = threadIdx.x;   // lane; owns column j = t+1, row t+1
    const float* ps = pred_strokes  + (size_t)b * SS * 10;
    const float* pv = pred_validity + (size_t)b * SS;
    const float* tg = targets      + (size_t)b * SS * 11;

    __shared__ float  Cs[SS * SS];     // cost (fp32 exact), [row][64]
    __shared__ float  tgs[SS * 11];    // staged targets
    __shared__ int    vidx[SS];        // compacted valid gt indices
    __shared__ int    col4row[SS];     // gt-row -> pred col

    // --- stage targets (coalesced) ---
#pragma unroll
    for (int k = 0; k < 11; ++k) tgs[k * SS + t] = tg[k * SS + t];
    LDS_FENCE();

    // --- valid compaction via ballot/rank ---
    const float gv    = tgs[t * 11 + 10];
    const bool  valid = gv > 0.5f;
    const unsigned long long vmask = __ballot(valid);
    const int ng = __popcll(vmask);
    if (valid) {
        const int rank = __popcll(vmask & ((1ull << t) - 1ull));
        vidx[rank] = t;
    }
    LDS_FENCE();

    // --- BCE term (slot t) ---
    double bterm;
    {
        const float pvv = pv[t];
        const float lp  = fmaxf(logf(pvv), -100.0f);
        const float l1p = fmaxf(logf(1.0f - pvv), -100.0f);
        bterm = -((double)gv * (double)lp + (double)(1.0f - gv) * (double)l1p);
    }

    double csum = 0.0, wsum = 0.0;

    if (ng > 0) {
        // --- cost matrix build + fused row-reduction claims ---
        float pr[10];
#pragma unroll
        for (int k = 0; k < 10; ++k) pr[k] = ps[t * 10 + k];

        double u_reg = 0.0;                 // u[t+1] (lane t = row t+1)
        int    p_j   = 0;                   // p[t+1]: matched row of column t+1
        unsigned long long colclaim = 0ull; // wave-uniform claimed-column mask
        unsigned long long freerows = 0ull; // wave-uniform free-row mask

        for (int i = 0; i < ng; ++i) {
            const float* g = &tgs[vidx[i] * 11];   // broadcast LDS reads
            float d[10];
#pragma unroll
            for (int k = 0; k < 10; ++k) d[k] = fabsf(pr[k] - g[k]);
            const float cs = ((d[0] + d[1]) + (d[2] + d[3]))
                           + ((d[4] + d[5]) + (d[6] + d[7]));   // numpy tree
            const float wd = d[8] + d[9];
            float c;
            {
#pragma clang fp contract(off)
                c = 5.0f * cs + wd;                // mul-then-add, no fma
            }
            Cs[i * SS + t] = c;

            // row min/argmin over the 64 columns (c >= 0: fp32 bits are
            // order-preserving as u32)
            const unsigned key = __float_as_uint(c);
            const unsigned kr  = wave_min_u32_to63(key);
            const unsigned mst = (unsigned)rlane_i((int)kr, 63);
            const unsigned long long rbal = __ballot(key == mst);
            const int jstar = __ffsll(rbal) - 1;   // 0-based argmin column
            if (t == i) u_reg = (double)__uint_as_float(mst);  // u[i+1]=rowmin
            if (!((colclaim >> jstar) & 1ull)) {   // claim if free
                colclaim |= 1ull << jstar;
                if (t == jstar) p_j = i + 1;       // tight edge, exactly 0
            } else {
                freerows |= 1ull << i;             // contested -> Dijkstra
            }
        }

        // --- JV Dijkstra phases for free rows; v starts at 0 (<= 0 inv.) ---
        double v_j = 0.0;   // v[t+1]

        while (freerows) {
            const int r0 = __ffsll(freerows) - 1;  // 0-based row, uniform
            freerows &= freerows - 1;
            const int i = r0 + 1;

            double minv_j   = __builtin_inf();
            int    way_j    = 0;
            bool   used_j   = false;
            bool   row_used = (t == r0);           // p[0] = i
            double u0       = rlane_d(u_reg, r0);  // u[i] = rowmin_i
            int    j0       = 0;
            float  Cval     = Cs[r0 * SS + t];

            for (;;) {
                used_j = used_j || (t + 1 == j0);
                const double cur = ((double)Cval - u0) - v_j;
                if (!used_j && cur < minv_j) { minv_j = cur; way_j = j0; }

                // wave argmin: order-preserving u32 map of the f64 hi-word
                const unsigned hraw = (unsigned)__double2hiint(minv_j);
                const bool     mneg = (hraw & 0x80000000u) != 0;
                const unsigned key  = used_j ? 0xFFFFFFFFu
                                    : (mneg ? ~hraw : (hraw | 0x80000000u));
                const unsigned kr    = wave_min_u32_to63(key);
                const unsigned hstar = (unsigned)rlane_i((int)kr, 63);
                unsigned long long bal = __ballot(key == hstar);
                int j1 = __ffsll(bal);                       // col = lane+1
                int i1 = rlane_i(p_j, j1 - 1);               // p[j1]

                // speculative prefetch of next C entry (correct unless the
                // rare exact-primary-tie below revises j1)
                float C_next = 0.0f;
                if (i1 != 0) C_next = Cs[(i1 - 1) * SS + t];

                if (__popcll(bal) > 1) {   // rare: resolve lo32 among ties
                    // tied lanes share the sign bit -> sign-mapped lo32
                    // comparison == full f64 comparison
                    const unsigned lraw = (unsigned)__double2loint(minv_j);
                    const unsigned lo   = (key == hstar)
                                        ? (mneg ? ~lraw : lraw) : 0xFFFFFFFFu;
                    const unsigned lr    = wave_min_u32_to63(lo);
                    const unsigned lstar = (unsigned)rlane_i((int)lr, 63);
                    bal = __ballot(key == hstar && lo == lstar);
                    j1  = __ffsll(bal);
                    i1  = rlane_i(p_j, j1 - 1);
                    if (i1 != 0) C_next = Cs[(i1 - 1) * SS + t];
                }

                const double delta  = rlane_d(minv_j, j1 - 1);
                const double u_next = (i1 != 0) ? rlane_d(u_reg, i1 - 1) : 0.0;
                // (row i1 not yet row_used this iteration, so u_next is
                //  unaffected by the predicated add below.)

                // dual/minv updates
                if (row_used) u_reg += delta;     // u[p[used]] += delta
                if (used_j)   v_j   -= delta;     // v[used]    -= delta
                else          minv_j -= delta;    // minv[unused] -= delta
                row_used = row_used || (t == i1 - 1);

                j0 = j1;
                if (i1 == 0) break;               // reached unmatched column
                u0 = u_next; Cval = C_next;
            }

            // --- augment along way[] (readlane pointer chase, short) ---
            int jj = j0;
            while (jj != 0) {
                const int jp   = rlane_i(way_j, jj - 1);
                const int pnew = (jp == 0) ? i : rlane_i(p_j, jp - 1);
                if (t == jj - 1) p_j = pnew;
                jj = jp;
            }
        }

        // --- extract assignment ---
        if (p_j > 0) col4row[p_j - 1] = t;
        LDS_FENCE();

        // --- matched L1 sums: thread t handles gt-row t (t < ng) ---
        if (t < ng) {
            const float* g  = &tgs[vidx[t] * 11];
            const float* mp = ps + col4row[t] * 10;
#pragma unroll
            for (int k = 0; k < 8; ++k) csum += (double)fabsf(mp[k] - g[k]);
            wsum = (double)fabsf(mp[8] - g[8]) + (double)fabsf(mp[9] - g[9]);
        }
    }

    // --- wave reductions (identical epilogue to rounds 1-6; cold path) ---
    double s0 = csum, s1 = wsum, s2 = bterm;
#pragma unroll
    for (int off = 1; off < 64; off <<= 1) {
        s0 += __shfl_xor(s0, off, 64);
        s1 += __shfl_xor(s1, off, 64);
        s2 += __shfl_xor(s2, off, 64);
    }
    if (t == 0) {
        const double bce = s2 / 64.0;
        const double loss = (ng > 0)
            ? 5.0 * (s0 / ((double)ng * 8.0)) + (s1 / ((double)ng * 2.0)) + bce
            : bce;
        loss_ws[b] = loss;
    }
}

__global__ __launch_bounds__(256) void detr_reduce_kernel(
    const double* __restrict__ ws, float* __restrict__ out, int B)
{
    const int t = threadIdx.x;
    double x = 0.0;
    for (int idx = t; idx < B; idx += 256) x += ws[idx];
    for (int off = 1; off < 64; off <<= 1) x += __shfl_xor(x, off, 64);
    __shared__ double part[4];
    if ((t & 63) == 0) part[t >> 6] = x;
    __syncthreads();
    if (t == 0) {
        double s = part[0] + part[1] + part[2] + part[3];
        out[0] = (float)(s / (double)B);
    }
}

extern "C" void kernel_launch(void* const* d_in, const int* in_sizes, int n_in,
                              void* d_out, int out_size, void* d_ws, size_t ws_size,
                              hipStream_t stream) {
    const float* ps = (const float*)d_in[0];
    const float* pv = (const float*)d_in[1];
    const float* tg = (const float*)d_in[2];
    float* out = (float*)d_out;
    double* ws = (double*)d_ws;
    const int B = in_sizes[0] / (SS * 10);

    detr_match_loss_kernel<<<B, SS, 0, stream>>>(ps, pv, tg, ws);
    detr_reduce_kernel<<<1, 256, 0, stream>>>(ws, out, B);
}